// Round 1
// baseline (276.199 us; speedup 1.0000x reference)
//
#include <hip/hip_runtime.h>

// Modulated deformable conv2d, fp32.
// B=4, C=64, H=W=128, O=64, K=3x3, stride=1, pad=1, dil=1, og=1, groups=1.
//
// Strategy (round 0): one thread per output pixel, acc[64] output channels in
// VGPRs. Per-tap bilinear corner addresses + (mask*validity*bilinear) weights
// precomputed once per pixel. Weights pre-transposed to [c][k][o] in d_ws so
// the inner 576-FMA loop reads wave-uniform, contiguous weights (scalarizable
// to s_load), making the VALU stream nearly pure v_fmac_f32.

#define BB 4
#define CC 64
#define HH 128
#define WW 128
#define OO 64
#define KHW 3
#define KK 9
#define HW (HH * WW)

__global__ void transpose_w_kernel(const float* __restrict__ w,
                                   float* __restrict__ wt) {
    int i = blockIdx.x * blockDim.x + threadIdx.x;
    if (i >= OO * CC * KK) return;
    // wt layout: [(c*9+k)*64 + o]
    int o  = i & (OO - 1);
    int ck = i >> 6;
    int c  = ck / KK;
    int k  = ck - c * KK;
    wt[i] = w[(o * CC + c) * KK + k];
}

__global__ __launch_bounds__(64) void deform_conv_kernel(
    const float* __restrict__ x, const float* __restrict__ offset,
    const float* __restrict__ mask, const float* __restrict__ wt,
    const float* __restrict__ bias, float* __restrict__ out) {
    int t = blockIdx.x * 64 + threadIdx.x;   // pixel id in [0, B*H*W)
    int b   = t >> 14;          // / (H*W)
    int rem = t & (HW - 1);
    int ho  = rem >> 7;         // / W
    int wo  = rem & (WW - 1);

    // Per-tap sampling setup: 4 corner addresses + 4 folded weights per tap.
    int   addr[KK][4];
    float wgt[KK][4];
    const float* xb = x + b * (CC * HW);

#pragma unroll
    for (int k = 0; k < KK; ++k) {
        float offy = offset[((b * (2 * KK) + 2 * k) * HW) + rem];
        float offx = offset[((b * (2 * KK) + 2 * k + 1) * HW) + rem];
        float m    = mask[((b * KK + k) * HW) + rem];
        float py = offy + (float)(k / KHW) + (float)(ho - 1);
        float px = offx + (float)(k % KHW) + (float)(wo - 1);
        float fy0 = floorf(py), fx0 = floorf(px);
        float ly = py - fy0, lx = px - fx0;
        int y0 = (int)fy0, x0 = (int)fx0;
        int y1 = y0 + 1, x1 = x0 + 1;
        bool vy0 = (y0 >= 0) && (y0 < HH);
        bool vy1 = (y1 >= 0) && (y1 < HH);
        bool vx0 = (x0 >= 0) && (x0 < WW);
        bool vx1 = (x1 >= 0) && (x1 < WW);
        int cy0 = min(max(y0, 0), HH - 1), cy1 = min(max(y1, 0), HH - 1);
        int cx0 = min(max(x0, 0), WW - 1), cx1 = min(max(x1, 0), WW - 1);
        addr[k][0] = cy0 * WW + cx0;
        addr[k][1] = cy0 * WW + cx1;
        addr[k][2] = cy1 * WW + cx0;
        addr[k][3] = cy1 * WW + cx1;
        wgt[k][0] = (vy0 && vx0) ? m * (1.0f - ly) * (1.0f - lx) : 0.0f;
        wgt[k][1] = (vy0 && vx1) ? m * (1.0f - ly) * lx : 0.0f;
        wgt[k][2] = (vy1 && vx0) ? m * ly * (1.0f - lx) : 0.0f;
        wgt[k][3] = (vy1 && vx1) ? m * ly * lx : 0.0f;
    }

    float acc[OO];
#pragma unroll
    for (int o = 0; o < OO; ++o) acc[o] = bias[o];

    for (int c = 0; c < CC; ++c) {
        const float* xc = xb + c * HW;
        float val[KK];
#pragma unroll
        for (int k = 0; k < KK; ++k) {
            val[k] = wgt[k][0] * xc[addr[k][0]] + wgt[k][1] * xc[addr[k][1]] +
                     wgt[k][2] * xc[addr[k][2]] + wgt[k][3] * xc[addr[k][3]];
        }
        const float* wrow = wt + c * (KK * OO);  // uniform address -> s_load
#pragma unroll
        for (int k = 0; k < KK; ++k) {
#pragma unroll
            for (int o = 0; o < OO; ++o) {
                acc[o] = fmaf(val[k], wrow[k * OO + o], acc[o]);
            }
        }
    }

    float* ob = out + b * (OO * HW) + rem;
#pragma unroll
    for (int o = 0; o < OO; ++o) ob[o * HW] = acc[o];  // coalesced per o
}

extern "C" void kernel_launch(void* const* d_in, const int* in_sizes, int n_in,
                              void* d_out, int out_size, void* d_ws,
                              size_t ws_size, hipStream_t stream) {
    const float* x      = (const float*)d_in[0];
    const float* offset = (const float*)d_in[1];
    const float* mask   = (const float*)d_in[2];
    const float* weight = (const float*)d_in[3];
    const float* bias   = (const float*)d_in[4];
    float* out = (float*)d_out;
    float* wt  = (float*)d_ws;  // 64*576*4 = 147456 bytes

    int nw = OO * CC * KK;
    transpose_w_kernel<<<(nw + 255) / 256, 256, 0, stream>>>(weight, wt);

    int npix = BB * HW;  // 65536
    deform_conv_kernel<<<npix / 64, 64, 0, stream>>>(x, offset, mask, wt, bias,
                                                     out);
}